// Round 3
// baseline (164.870 us; speedup 1.0000x reference)
//
#include <hip/hip_runtime.h>

// HBilinearUpsample: Poincare-ball geodesic-midpoint 2x upsample.
// midpoint(x,y) = A*x + B*y with A,B functions of (|x|^2,|y|^2,x.y) only;
// the 2x2-cell center = midpoint(midpoint(x00,x10), midpoint(x01,x11)) is a
// linear combo of the 4 corners via the cell's 4x4 Gram matrix (reduction
// axis = channels). Edge replication == clamped index (midpoint(x,x)=x).
//
// R2 vs R1 (163.7us total, kernel <78us hiding under the 78us harness
// poison fills): R1's occupancy fix (8->32 waves/CU) was a no-op, so the
// kernel is NOT latency-bound; theory: it is memory-instruction/transaction
// bound (192 mem-instr/thread, two full read passes, 4B-granule reads).
// R2: lane owns 2 cells via float2 loads (512B wave read bursts),
// neighbors via shfl (no overlapping reloads), input retained in registers
// (second pass reads deleted), shared Gram accumulators (17/lane),
// coefficients computed once by wave0 and LDS-broadcast, float4 stores
// (1KB wave write bursts). 16 loads + 16 stores + ~33 LDS ops per thread.
// (R3 = R2 resubmitted: R2 never ran — GPU broker timeout.)

#define EPSF   1e-15f
#define MAXAT  0.99999f

__device__ __forceinline__ void midcoef(float x2, float y2, float xy,
                                        float& A, float& B) {
    float alpha  = 1.0f - 2.0f * xy + y2;
    float beta   = 1.0f - x2;
    float den_w  = fmaxf(1.0f - 2.0f * xy + x2 * y2, EPSF);
    float inv_dw = 1.0f / den_w;
    // dot(x, w)
    float dxw = (beta * xy - alpha * x2) * inv_dw;
    // |w|^2
    float wn2 = (alpha * alpha * x2 - 2.0f * alpha * beta * xy + beta * beta * y2)
                * inv_dw * inv_dw;
    wn2 = fmaxf(wn2, EPSF);
    float wn = sqrtf(wn2);
    float a  = fminf(wn, MAXAT);
    float s  = a / (1.0f + sqrtf(fmaxf(1.0f - a * a, 0.0f)));  // tanh(atanh(a)/2)
    float t  = s / wn;                 // second = t * w
    float xs = t * dxw;                // dot(x, second)
    float s2 = t * t * wn2;            // |second|^2
    float den     = fmaxf(1.0f + 2.0f * xs + x2 * s2, EPSF);
    float inv_den = 1.0f / den;
    float k = beta * t * inv_dw;
    A = ((1.0f + 2.0f * xs + s2) - k * alpha) * inv_den;
    B = (k * beta) * inv_den;
}

constexpr int Bn = 8, Cn = 64, Hn = 128, Wn = 128;
constexpr int CS  = Hn * Wn;       // input channel stride (elems)
constexpr int CG  = 8;             // channel-group waves per block
constexpr int CPG = Cn / CG;       // 8 channels per group
constexpr int NA  = 17;            // Gram accumulators per lane (2 cells, shared terms)
constexpr int NCF = 16;            // coefficients per lane (2 cells x 8)

__global__ __launch_bounds__(512, 4)
void hupsample_v2(const float* __restrict__ x, float* __restrict__ out) {
    __shared__ float sums[CG * 64 * NA];       // 34.0 KB, stride 17 (odd, conflict-free)
    __shared__ float coefs[64 * (NCF + 1)];    // 4.25 KB, stride 17

    // XCD swizzle: 1024 blocks = 8 XCDs x 128; each XCD gets one full batch
    // image (4 MB = its L2); consecutive idx -> consecutive h (row reuse).
    const int lin = blockIdx.x;
    const int swz = (lin & 7) * 128 + (lin >> 3);
    const int h = swz & (Hn - 1);              // 0..127
    const int b = swz >> 7;                    // 0..7

    const int wl = threadIdx.x & 63;           // lane: owns cells w=2wl, 2wl+1
    const int cg = threadIdx.x >> 6;           // 0..7 channel group (one wave)
    const int hp = (h + 1 < Hn) ? (h + 1) : (Hn - 1);

    const float* xg = x + (size_t)b * Cn * CS + (size_t)cg * CPG * CS;
    const float2* row0 = (const float2*)(xg + (size_t)h  * Wn) + wl;
    const float2* row1 = (const float2*)(xg + (size_t)hp * Wn) + wl;

    // ---- single read pass: load float2 pairs, accumulate shared Grams ----
    // cell0 corners: (r0.x, r0.y | r1.x, r1.y); cell1: (r0.y, n0 | r1.y, n1)
    float2 R0[CPG], R1[CPG];
    float q00=0.f,q01=0.f,q02=0.f,q10=0.f,q11=0.f,q12=0.f;   // squares
    float h0=0.f,h1=0.f,g0=0.f,g1=0.f;                       // horizontal dots
    float v0=0.f,v1=0.f,v2=0.f;                              // vertical dots
    float dx0=0.f,dx1=0.f,dy0=0.f,dy1=0.f;                   // diagonal dots
#pragma unroll
    for (int c = 0; c < CPG; ++c) {
        float2 r0 = row0[c * (CS / 2)];
        float2 r1 = row1[c * (CS / 2)];
        R0[c] = r0;  R1[c] = r1;
        float n0 = __shfl_down(r0.x, 1);
        float n1 = __shfl_down(r1.x, 1);
        if (wl == 63) { n0 = r0.y; n1 = r1.y; }   // w-clamp at image edge
        q00 += r0.x * r0.x;  q01 += r0.y * r0.y;  q02 += n0 * n0;
        q10 += r1.x * r1.x;  q11 += r1.y * r1.y;  q12 += n1 * n1;
        h0  += r0.x * r0.y;  h1  += r0.y * n0;
        g0  += r1.x * r1.y;  g1  += r1.y * n1;
        v0  += r0.x * r1.x;  v1  += r0.y * r1.y;  v2 += n0 * n1;
        dx0 += r0.x * r1.y;  dx1 += r0.y * n1;
        dy0 += r0.y * r1.x;  dy1 += n0 * r1.y;
    }

    {
        float* my = &sums[(cg * 64 + wl) * NA];
        my[0]=q00;  my[1]=q01;  my[2]=q02;  my[3]=q10;  my[4]=q11;  my[5]=q12;
        my[6]=h0;   my[7]=h1;   my[8]=g0;   my[9]=g1;
        my[10]=v0;  my[11]=v1;  my[12]=v2;
        my[13]=dx0; my[14]=dx1; my[15]=dy0; my[16]=dy1;
    }
    __syncthreads();

    // ---- wave 0 combines the 8 group-partials and computes coefficients ----
    if (cg == 0) {
        float s_[NA];
#pragma unroll
        for (int k = 0; k < NA; ++k) s_[k] = 0.f;
#pragma unroll
        for (int g = 0; g < CG; ++g) {
            const float* r = &sums[(g * 64 + wl) * NA];
#pragma unroll
            for (int k = 0; k < NA; ++k) s_[k] += r[k];
        }
        float Q00=s_[0],Q01=s_[1],Q02=s_[2],Q10=s_[3],Q11=s_[4],Q12=s_[5];
        float H0=s_[6],H1=s_[7],G0=s_[8],G1=s_[9];
        float V0=s_[10],V1=s_[11],V2=s_[12];
        float X0=s_[13],X1=s_[14],Y0=s_[15],Y1=s_[16];

        float* cf = &coefs[wl * (NCF + 1)];
        {   // cell 0: Gram = (Q00,Q01 | Q10,Q11), dots (H0,G0,V0,X0,Y0,V1)
            float Ah,Bh; midcoef(Q00, Q01, H0, Ah, Bh);
            float A2,B2; midcoef(Q10, Q11, G0, A2, B2);
            float Av,Bv; midcoef(Q00, Q10, V0, Av, Bv);
            float a2 = Ah*Ah*Q00 + 2.f*Ah*Bh*H0 + Bh*Bh*Q01;
            float b2 = A2*A2*Q10 + 2.f*A2*B2*G0 + B2*B2*Q11;
            float ab = Ah*A2*V0 + Ah*B2*X0 + Bh*A2*Y0 + Bh*B2*V1;
            float A3,B3; midcoef(a2, b2, ab, A3, B3);
            cf[0]=Ah; cf[1]=Bh; cf[2]=Av; cf[3]=Bv;
            cf[4]=A3*Ah; cf[5]=A3*Bh; cf[6]=B3*A2; cf[7]=B3*B2;
        }
        {   // cell 1: Gram = (Q01,Q02 | Q11,Q12), dots (H1,G1,V1,X1,Y1,V2)
            float Ah,Bh; midcoef(Q01, Q02, H1, Ah, Bh);
            float A2,B2; midcoef(Q11, Q12, G1, A2, B2);
            float Av,Bv; midcoef(Q01, Q11, V1, Av, Bv);
            float a2 = Ah*Ah*Q01 + 2.f*Ah*Bh*H1 + Bh*Bh*Q02;
            float b2 = A2*A2*Q11 + 2.f*A2*B2*G1 + B2*B2*Q12;
            float ab = Ah*A2*V1 + Ah*B2*X1 + Bh*A2*Y1 + Bh*B2*V2;
            float A3,B3; midcoef(a2, b2, ab, A3, B3);
            cf[8]=Ah;  cf[9]=Bh;  cf[10]=Av; cf[11]=Bv;
            cf[12]=A3*Ah; cf[13]=A3*Bh; cf[14]=B3*A2; cf[15]=B3*B2;
        }
    }
    __syncthreads();

    float Ah0,Bh0,Av0,Bv0,CA0,CB0,CC0,CD0;
    float Ah1,Bh1,Av1,Bv1,CA1,CB1,CC1,CD1;
    {
        const float* cf = &coefs[wl * (NCF + 1)];
        Ah0=cf[0];  Bh0=cf[1];  Av0=cf[2];  Bv0=cf[3];
        CA0=cf[4];  CB0=cf[5];  CC0=cf[6];  CD0=cf[7];
        Ah1=cf[8];  Bh1=cf[9];  Av1=cf[10]; Bv1=cf[11];
        CA1=cf[12]; CB1=cf[13]; CC1=cf[14]; CD1=cf[15];
    }

    // ---- emit pass: registers only, float4 stores (wave = full 1KB row) ----
    float* og = out + (size_t)b * Cn * 4 * CS + (size_t)cg * CPG * 4 * CS;
    float4* o0 = (float4*)(og + (size_t)(2 * h)     * (2 * Wn)) + wl;
    float4* o1 = (float4*)(og + (size_t)(2 * h + 1) * (2 * Wn)) + wl;
#pragma unroll
    for (int c = 0; c < CPG; ++c) {
        float2 r0 = R0[c], r1 = R1[c];
        float n0 = __shfl_down(r0.x, 1);
        float n1 = __shfl_down(r1.x, 1);
        if (wl == 63) { n0 = r0.y; n1 = r1.y; }
        float oh0 = Ah0 * r0.x + Bh0 * r0.y;
        float oh1 = Ah1 * r0.y + Bh1 * n0;
        float ov0 = Av0 * r0.x + Bv0 * r1.x;
        float ov1 = Av1 * r0.y + Bv1 * r1.y;
        float oc0 = CA0 * r0.x + CB0 * r0.y + CC0 * r1.x + CD0 * r1.y;
        float oc1 = CA1 * r0.y + CB1 * n0  + CC1 * r1.y + CD1 * n1;
        o0[c * CS] = make_float4(r0.x, oh0, r0.y, oh1);   // row 2h
        o1[c * CS] = make_float4(ov0, oc0, ov1, oc1);     // row 2h+1
    }
}

extern "C" void kernel_launch(void* const* d_in, const int* in_sizes, int n_in,
                              void* d_out, int out_size, void* d_ws, size_t ws_size,
                              hipStream_t stream) {
    const float* x = (const float*)d_in[0];
    float* out = (float*)d_out;
    hipLaunchKernelGGL(hupsample_v2, dim3(1024), dim3(512), 0, stream, x, out);
}